// Round 8
// baseline (197.606 us; speedup 1.0000x reference)
//
#include <hip/hip_runtime.h>

#define SEQ 2048
#define CDIM 1024
#define NHEAD 16
#define HDIM 64

typedef __bf16 bf16x8 __attribute__((ext_vector_type(8)));
typedef __bf16 bf16x4v __attribute__((ext_vector_type(4)));
typedef float f32x4 __attribute__((ext_vector_type(4)));

typedef const __attribute__((address_space(1))) char* gcp_t;
typedef __attribute__((address_space(3))) char* lcp_t;

__device__ __forceinline__ void gload16(const void* g, void* l) {
    __builtin_amdgcn_global_load_lds((gcp_t)g, (lcp_t)l, 16, 0, 0);
}

__device__ __forceinline__ unsigned short f2bf(float f) {
    unsigned int u = __float_as_uint(f);
    u += 0x7fffu + ((u >> 16) & 1u);
    return (unsigned short)(u >> 16);
}

// GEMM LDS swizzle (proven: zero bank conflicts in r6/r7): rows are 64 B; row
// bit0 alternates 64B halves, bits 1-2 rotate 16B slots. Applied on the
// pre-swizzled global source (gload dest linear) and identically on ds_read.
__device__ __forceinline__ int swz16(int r) { return ((r >> 1) & 3) << 4; }

// ---------------- precompute kernels ----------------

__global__ void cvt_kernel(const float* __restrict__ src, unsigned short* __restrict__ dst, int n4) {
    int i = blockIdx.x * blockDim.x + threadIdx.x;
    if (i < n4) {
        float4 v = ((const float4*)src)[i];
        ushort4 o;
        o.x = f2bf(v.x); o.y = f2bf(v.y); o.z = f2bf(v.z); o.w = f2bf(v.w);
        ((ushort4*)dst)[i] = o;
    }
}

// all four weight matrices in one launch
__global__ void cvtw_kernel(const float* __restrict__ Wq, const float* __restrict__ Wk,
                            const float* __restrict__ Wv, const float* __restrict__ Wp,
                            unsigned short* __restrict__ wqkv, unsigned short* __restrict__ wpb) {
    int i = blockIdx.x * blockDim.x + threadIdx.x;  // 4 * 262144 float4 groups
    int which = i >> 18, r = i & 262143;
    const float* s = (which == 0) ? Wq : (which == 1) ? Wk : (which == 2) ? Wv : Wp;
    unsigned short* d = (which < 3) ? (wqkv + (size_t)which * 1048576) : wpb;
    float4 v = ((const float4*)s)[r];
    ushort4 o;
    o.x = f2bf(v.x); o.y = f2bf(v.y); o.z = f2bf(v.z); o.w = f2bf(v.w);
    ((ushort4*)d)[r] = o;
}

// interleaved (cos,sin) table: cstab[t*32+j] = {cos, sin}
__global__ void rope_kernel(float2* __restrict__ cstab) {
    int idx = blockIdx.x * blockDim.x + threadIdx.x;  // 2048*32
    int j = idx & 31, t = idx >> 5;
    // faithful to ref: theta = 1 / 10000**(-2*(j-1)/64), all f32 roundings reproduced
    float e = -2.0f * ((float)j - 1.0f) / 64.0f;
    float denom = (float)pow(10000.0, (double)e);
    float theta = 1.0f / denom;
    float ang = (float)t * theta;
    cstab[idx] = make_float2(cosf(ang), sinf(ang));
}

// ---------------- GEMM (C = A * B^T), BK=32, 2-phase dbuf + swz16 ----------
// MODE 0 (BM=128): A=x[4096][1024], B=Wqkv[3072][1024]; bias+RoPE epilogue,
//   q (pre-scaled 0.125*log2e), k as [B,H,T,D] bf16, v^T as [B,H,D,T] bf16.
// MODE 1 (BM=64): A=y[4096][1024], B=Wp[1024][1024]; bias, f32 out.
template <int MODE, int BM>
__global__ __launch_bounds__(256) void gemm_bt(
    const unsigned short* __restrict__ A, const unsigned short* __restrict__ Bm,
    const float* __restrict__ b0, const float* __restrict__ b1, const float* __restrict__ b2,
    unsigned short* __restrict__ qb, unsigned short* __restrict__ kb,
    unsigned short* __restrict__ vtb, float* __restrict__ outf,
    const float2* __restrict__ cstab)
{
    constexpr int K = 1024;
    constexpr int NIT = K / 32;
    constexpr int NR = (BM == 128) ? 4 : 2;
    __shared__ __align__(16) char As[2][BM * 64];
    __shared__ __align__(16) char Bs[2][128 * 64];
    const int tid = threadIdx.x, lane = tid & 63, wid = tid >> 6;
    const int m0 = blockIdx.y * BM, n0 = blockIdx.x * 128;
    const int wr = (BM == 128) ? ((wid >> 1) * 64) : 0;
    const int wc = (BM == 128) ? ((wid & 1) * 64) : (wid * 32);

    f32x4 acc[4][NR] = {};

    const char* Ag = (const char*)(A + (size_t)m0 * K);
    const char* Bg = (const char*)(Bm + (size_t)n0 * K);
    const int r0 = tid >> 2, cb = (tid & 3) * 16;
    const int ldsw = wid << 10;

    auto stage = [&](int k0, int bufi) {
        char* Ad = As[bufi];
        char* Bd = Bs[bufi];
        gload16(Ag + (size_t)r0 * 2048 + k0 * 2 + (cb ^ swz16(r0)), Ad + ldsw);
        if constexpr (BM == 128)
            gload16(Ag + (size_t)(r0 + 64) * 2048 + k0 * 2 + (cb ^ swz16(r0 + 64)), Ad + 4096 + ldsw);
        gload16(Bg + (size_t)r0 * 2048 + k0 * 2 + (cb ^ swz16(r0)), Bd + ldsw);
        gload16(Bg + (size_t)(r0 + 64) * 2048 + k0 * 2 + (cb ^ swz16(r0 + 64)), Bd + 4096 + ldsw);
    };

    stage(0, 0);
    __syncthreads();

    for (int it = 0; it < NIT; ++it) {
        const int cur = it & 1;
        if (it + 1 < NIT) stage((it + 1) * 32, cur ^ 1);
        const char* Ac = As[cur];
        const char* Bc = Bs[cur];
        const int fs = (lane >> 4) * 16;
        bf16x8 af[4], bfr[NR];
#pragma unroll
        for (int am = 0; am < 4; ++am) {
            const int r = wr + am * 16 + (lane & 15);
            af[am] = *(const bf16x8*)(Ac + r * 64 + (fs ^ swz16(r)));
        }
#pragma unroll
        for (int an = 0; an < NR; ++an) {
            const int r = wc + an * 16 + (lane & 15);
            bfr[an] = *(const bf16x8*)(Bc + r * 64 + (fs ^ swz16(r)));
        }
#pragma unroll
        for (int am = 0; am < 4; ++am)
#pragma unroll
            for (int an = 0; an < NR; ++an)
                acc[am][an] = __builtin_amdgcn_mfma_f32_16x16x32_bf16(af[am], bfr[an], acc[am][an], 0, 0, 0);
        __syncthreads();
    }

    if (MODE == 0) {
        const float QSCL = 0.18033688011112042f;  // 0.125 * log2(e)
#pragma unroll
        for (int an = 0; an < NR; ++an) {
            const int ng = n0 + wc + an * 16 + (lane & 15);
            const int which = ng >> 10, nl = ng & 1023;
            const int h = nl >> 6, d = nl & 63;
            const float* bptr = (which == 0) ? b0 : (which == 1) ? b1 : b2;
            const float bias = bptr[nl];
            if (which < 2) {
                unsigned short* dst = (which == 0) ? qb : kb;
                const float qs = (which == 0) ? QSCL : 1.0f;
                const int j = d >> 1;
#pragma unroll
                for (int am = 0; am < 4; ++am) {
#pragma unroll
                    for (int i = 0; i < 4; ++i) {
                        const int row = m0 + wr + am * 16 + (lane >> 4) * 4 + i;
                        const int bb = row >> 11, t = row & 2047;
                        float v = acc[am][an][i] + bias;
                        float p = __shfl_xor(v, 1);
                        const float2 cs = cstab[t * 32 + j];
                        v = (d & 1) ? fmaf(v, cs.x, p * cs.y) : fmaf(v, cs.x, -p * cs.y);
                        dst[((size_t)((bb * 16 + h) * 2048 + t)) * 64 + d] = f2bf(v * qs);
                    }
                }
            } else {
#pragma unroll
                for (int am = 0; am < 4; ++am) {
                    const int rowb = m0 + wr + am * 16 + (lane >> 4) * 4;
                    const int bb = rowb >> 11, t = rowb & 2047;
                    ushort4 pk;
                    pk.x = f2bf(acc[am][an][0] + bias);
                    pk.y = f2bf(acc[am][an][1] + bias);
                    pk.z = f2bf(acc[am][an][2] + bias);
                    pk.w = f2bf(acc[am][an][3] + bias);
                    *(ushort4*)(vtb + ((size_t)((bb * 16 + h) * 64 + d)) * 2048 + t) = pk;
                }
            }
        }
    } else {
#pragma unroll
        for (int an = 0; an < NR; ++an) {
            const int col = n0 + wc + an * 16 + (lane & 15);
            const float bias = b0[col];
#pragma unroll
            for (int am = 0; am < 4; ++am)
#pragma unroll
                for (int i = 0; i < 4; ++i) {
                    const int row = m0 + wr + am * 16 + (lane >> 4) * 4 + i;
                    outf[(size_t)row * 1024 + col] = acc[am][an][i] + bias;
                }
        }
    }
}

// ---------------- flash attention: barrier-free, K/V direct from L2 -------
// 1-D grid 512 blocks (XCD-bijective swizzle: each XCD owns 4 heads -> its
// K/V slice = 2MB, L2-resident). 4 waves/block, each wave owns 32 q rows and
// free-runs its full causal sweep — NO __syncthreads anywhere. K and V MFMA
// fragments are loaded straight from global (L2-hit); only per-wave P lives
// in LDS (8KB/block). qt map pairs long+short blocks on adjacent IDs.
// Exactly 2048 waves = 2/SIMD all-resident; VGPR-capped via launch_bounds.
__global__ __launch_bounds__(256, 2) void attn_kernel(
    const unsigned short* __restrict__ qb, const unsigned short* __restrict__ kb,
    const unsigned short* __restrict__ vtb, unsigned short* __restrict__ yb)
{
    __shared__ __align__(16) unsigned short Ps[4][32 * 64];
    const int tid = threadIdx.x, lane = tid & 63, wid = tid >> 6;
    const int bid = blockIdx.x;
    const int wg = (bid & 7) * 64 + (bid >> 3);      // XCD-contiguous (512%8==0)
    const int bh = wg >> 4;
    const int xx = wg & 15;
    const int qt = (xx & 1) ? (15 - (xx >> 1)) : (xx >> 1);  // pair long+short
    const int b = bh >> 4, h = bh & 15;
    const int qw = qt * 128 + wid * 32;

    const unsigned short* Qg = qb + (size_t)bh * SEQ * HDIM;
    const char* Kg = (const char*)(kb + (size_t)bh * SEQ * HDIM);
    const char* Vg = (const char*)(vtb + (size_t)bh * HDIM * SEQ);
    const char* Kbase = Kg + (lane & 15) * 128 + (lane >> 4) * 16;
    const char* Vbase = Vg + (lane & 15) * 4096 + (lane >> 4) * 16;

    // Q fragments (q pre-scaled by 0.125*log2e in GEMM epilogue)
    bf16x8 qf[2][2];
#pragma unroll
    for (int am = 0; am < 2; ++am)
#pragma unroll
        for (int kf = 0; kf < 2; ++kf)
            qf[am][kf] = *(const bf16x8*)(Qg + (size_t)(qw + am * 16 + (lane & 15)) * 64 + kf * 32 + (lane >> 4) * 8);

    f32x4 o[4][2] = {};              // o[dn][am] : O^T[d][q]
    float mrun[2] = {-3e38f, -3e38f};
    float lrun[2] = {0.0f, 0.0f};
    const int nt = (qw >> 6) + 1;

    bf16x8 ka[4][2], kn[4][2], vf[4][2];
    // preload K fragments for tile 0
#pragma unroll
    for (int an = 0; an < 4; ++an)
#pragma unroll
        for (int kf = 0; kf < 2; ++kf)
            ka[an][kf] = *(const bf16x8*)(Kbase + an * 2048 + kf * 64);

    for (int kt = 0; kt < nt; ++kt) {
        const int kv0 = kt * 64;
        // issue V loads for this tile early (needed only after softmax)
#pragma unroll
        for (int dn = 0; dn < 4; ++dn)
#pragma unroll
            for (int kf = 0; kf < 2; ++kf)
                vf[dn][kf] = *(const bf16x8*)(Vbase + dn * 65536 + kv0 * 2 + kf * 64);
        // QK^T (swapped): s[an][am] = S^T tile, lane-local kv rows
        f32x4 s[4][2] = {};
        __builtin_amdgcn_s_setprio(1);
#pragma unroll
        for (int kf = 0; kf < 2; ++kf)
#pragma unroll
            for (int an = 0; an < 4; ++an)
#pragma unroll
                for (int am = 0; am < 2; ++am)
                    s[an][am] = __builtin_amdgcn_mfma_f32_16x16x32_bf16(ka[an][kf], qf[am][kf], s[an][am], 0, 0, 0);
        __builtin_amdgcn_s_setprio(0);
        // prefetch next tile's K during softmax
        if (kt + 1 < nt) {
            const char* Kt = Kbase + (size_t)(kv0 + 64) * 128;
#pragma unroll
            for (int an = 0; an < 4; ++an)
#pragma unroll
                for (int kf = 0; kf < 2; ++kf)
                    kn[an][kf] = *(const bf16x8*)(Kt + an * 2048 + kf * 64);
        }
        const bool need_mask = (kv0 + 63 > qw);
#pragma unroll
        for (int am = 0; am < 2; ++am) {
            const int qg = qw + am * 16 + (lane & 15);
            const int kbase = kv0 + ((lane >> 4) << 2);
            float p[4][4];
            float mx = -3e38f;
#pragma unroll
            for (int an = 0; an < 4; ++an)
#pragma unroll
                for (int i = 0; i < 4; ++i) {
                    float v = s[an][am][i];
                    if (need_mask && (kbase + an * 16 + i > qg)) v = -3e38f;
                    p[an][i] = v;
                    mx = fmaxf(mx, v);
                }
            mx = fmaxf(mx, __shfl_xor(mx, 16));
            mx = fmaxf(mx, __shfl_xor(mx, 32));
            // defer-max (T13): only rescale when max grew by > 8 (log2 units)
            if (!__all(mx <= mrun[am] + 8.0f)) {
                const float mnew = fmaxf(mrun[am], mx);
                const float fsc = __builtin_amdgcn_exp2f(mrun[am] - mnew);
                lrun[am] *= fsc;
#pragma unroll
                for (int dn = 0; dn < 4; ++dn) o[dn][am] *= fsc;
                mrun[am] = mnew;
            }
            float rs = 0.0f;
#pragma unroll
            for (int an = 0; an < 4; ++an)
#pragma unroll
                for (int i = 0; i < 4; ++i) {
                    p[an][i] = __builtin_amdgcn_exp2f(p[an][i] - mrun[am]);
                    rs += p[an][i];
                }
            rs += __shfl_xor(rs, 16);
            rs += __shfl_xor(rs, 32);
            lrun[am] += rs;
            // write P[q][kv] packed (4x ds_write_b64), swizzled; per-wave region
            const int ql = am * 16 + (lane & 15);
            char* pbs = (char*)Ps[wid] + ql * 128;
            const int xr = (ql & 7) << 4;
            const int gb = (lane >> 4) << 3;
#pragma unroll
            for (int an = 0; an < 4; ++an) {
                bf16x4v pk;
                pk[0] = (__bf16)p[an][0]; pk[1] = (__bf16)p[an][1];
                pk[2] = (__bf16)p[an][2]; pk[3] = (__bf16)p[an][3];
                *(bf16x4v*)(pbs + ((an * 32 + gb) ^ xr)) = pk;
            }
        }
        // PV: O^T += V^T * P^T  (same-wave LDS read; compiler orders via lgkmcnt)
        __builtin_amdgcn_s_setprio(1);
#pragma unroll
        for (int kf = 0; kf < 2; ++kf) {
            bf16x8 pf[2];
#pragma unroll
            for (int am = 0; am < 2; ++am) {
                const int ql = am * 16 + (lane & 15);
                pf[am] = *(const bf16x8*)((const char*)Ps[wid] + ql * 128 + ((kf * 64 + (lane >> 4) * 16) ^ ((ql & 7) << 4)));
            }
#pragma unroll
            for (int dn = 0; dn < 4; ++dn)
#pragma unroll
                for (int am = 0; am < 2; ++am)
                    o[dn][am] = __builtin_amdgcn_mfma_f32_16x16x32_bf16(vf[dn][kf], pf[am], o[dn][am], 0, 0, 0);
        }
        __builtin_amdgcn_s_setprio(0);
        // rotate prefetched K into place
        if (kt + 1 < nt) {
#pragma unroll
            for (int an = 0; an < 4; ++an)
#pragma unroll
                for (int kf = 0; kf < 2; ++kf)
                    ka[an][kf] = kn[an][kf];
        }
    }

    // epilogue: normalized direct y write
#pragma unroll
    for (int am = 0; am < 2; ++am) {
        const float inv = 1.0f / lrun[am];
        const int qg = qw + am * 16 + (lane & 15);
        unsigned short* yrow = yb + (size_t)(b * SEQ + qg) * CDIM + h * 64;
#pragma unroll
        for (int dn = 0; dn < 4; ++dn) {
            const int d = dn * 16 + ((lane >> 4) << 2);
            bf16x4v pk;
            pk[0] = (__bf16)(o[dn][am][0] * inv);
            pk[1] = (__bf16)(o[dn][am][1] * inv);
            pk[2] = (__bf16)(o[dn][am][2] * inv);
            pk[3] = (__bf16)(o[dn][am][3] * inv);
            *(bf16x4v*)(yrow + d) = pk;
        }
    }
}

// ---------------- host ----------------

extern "C" void kernel_launch(void* const* d_in, const int* in_sizes, int n_in,
                              void* d_out, int out_size, void* d_ws, size_t ws_size,
                              hipStream_t stream) {
    (void)in_sizes; (void)n_in; (void)out_size; (void)ws_size;
    const float* x  = (const float*)d_in[0];
    const float* Wq = (const float*)d_in[1];
    const float* bq = (const float*)d_in[2];
    const float* Wk = (const float*)d_in[3];
    const float* bk = (const float*)d_in[4];
    const float* Wv = (const float*)d_in[5];
    const float* bv = (const float*)d_in[6];
    const float* Wp = (const float*)d_in[7];
    const float* bp = (const float*)d_in[8];
    float* out = (float*)d_out;

    char* ws = (char*)d_ws;
    size_t off = 0;
    auto take = [&](size_t bytes) -> char* {
        char* p = ws + off;
        off = (off + bytes + 255) & ~(size_t)255;
        return p;
    };
    float2* cstab = (float2*)take((size_t)SEQ * 32 * 8);
    unsigned short* xb   = (unsigned short*)take((size_t)4096 * 1024 * 2);
    unsigned short* wqkv = (unsigned short*)take((size_t)3 * 1024 * 1024 * 2);
    unsigned short* wpb  = (unsigned short*)take((size_t)1024 * 1024 * 2);
    unsigned short* qbuf = (unsigned short*)take((size_t)32 * SEQ * HDIM * 2);
    unsigned short* kbuf = (unsigned short*)take((size_t)32 * SEQ * HDIM * 2);
    unsigned short* vtb  = (unsigned short*)take((size_t)32 * HDIM * SEQ * 2);
    unsigned short* yb   = (unsigned short*)take((size_t)4096 * 1024 * 2);

    rope_kernel<<<256, 256, 0, stream>>>(cstab);
    cvt_kernel<<<4096, 256, 0, stream>>>(x, xb, 1048576);
    cvtw_kernel<<<4096, 256, 0, stream>>>(Wq, Wk, Wv, Wp, wqkv, wpb);

    dim3 g0(24, 32);
    gemm_bt<0, 128><<<g0, 256, 0, stream>>>(xb, wqkv, bq, bk, bv, qbuf, kbuf, vtb, nullptr, cstab);
    attn_kernel<<<512, 256, 0, stream>>>(qbuf, kbuf, vtb, yb);
    dim3 g2(8, 64);
    gemm_bt<1, 64><<<g2, 256, 0, stream>>>(yb, wpb, bp, nullptr, nullptr, nullptr, nullptr, nullptr, out, cstab);
}

// Round 9
// 134.223 us; speedup vs baseline: 1.4722x; 1.4722x over previous
//
#include <hip/hip_runtime.h>

#define SEQ 2048
#define CDIM 1024
#define NHEAD 16
#define HDIM 64

typedef __bf16 bf16x8 __attribute__((ext_vector_type(8)));
typedef __bf16 bf16x4v __attribute__((ext_vector_type(4)));
typedef float f32x4 __attribute__((ext_vector_type(4)));

typedef const __attribute__((address_space(1))) char* gcp_t;
typedef __attribute__((address_space(3))) char* lcp_t;

__device__ __forceinline__ void gload16(const void* g, void* l) {
    __builtin_amdgcn_global_load_lds((gcp_t)g, (lcp_t)l, 16, 0, 0);
}

__device__ __forceinline__ unsigned short f2bf(float f) {
    unsigned int u = __float_as_uint(f);
    u += 0x7fffu + ((u >> 16) & 1u);
    return (unsigned short)(u >> 16);
}

// 64B-row LDS swizzle for the 128^2 proj GEMM (proven zero conflicts r6/r7)
__device__ __forceinline__ int swz16(int r) { return ((r >> 1) & 3) << 4; }

// ---------------- precompute kernels ----------------

__global__ void cvt_kernel(const float* __restrict__ src, unsigned short* __restrict__ dst, int n4) {
    int i = blockIdx.x * blockDim.x + threadIdx.x;
    if (i < n4) {
        float4 v = ((const float4*)src)[i];
        ushort4 o;
        o.x = f2bf(v.x); o.y = f2bf(v.y); o.z = f2bf(v.z); o.w = f2bf(v.w);
        ((ushort4*)dst)[i] = o;
    }
}

__global__ void cvtw_kernel(const float* __restrict__ Wq, const float* __restrict__ Wk,
                            const float* __restrict__ Wv, const float* __restrict__ Wp,
                            unsigned short* __restrict__ wqkv, unsigned short* __restrict__ wpb) {
    int i = blockIdx.x * blockDim.x + threadIdx.x;  // 4 * 262144 float4 groups
    int which = i >> 18, r = i & 262143;
    const float* s = (which == 0) ? Wq : (which == 1) ? Wk : (which == 2) ? Wv : Wp;
    unsigned short* d = (which < 3) ? (wqkv + (size_t)which * 1048576) : wpb;
    float4 v = ((const float4*)s)[r];
    ushort4 o;
    o.x = f2bf(v.x); o.y = f2bf(v.y); o.z = f2bf(v.z); o.w = f2bf(v.w);
    ((ushort4*)d)[r] = o;
}

// interleaved (cos,sin) table: cstab[t*32+j] = {cos, sin}
__global__ void rope_kernel(float2* __restrict__ cstab) {
    int idx = blockIdx.x * blockDim.x + threadIdx.x;  // 2048*32
    int j = idx & 31, t = idx >> 5;
    float e = -2.0f * ((float)j - 1.0f) / 64.0f;
    float denom = (float)pow(10000.0, (double)e);
    float theta = 1.0f / denom;
    float ang = (float)t * theta;
    cstab[idx] = make_float2(cosf(ang), sinf(ang));
}

// ---------------- QKV GEMM: 256x256 tile, BK=64, 8 waves, 4 sub-phases ----
// C = x * Wqkv^T (M=4096, N=3072, K=1024). LDS 128KB: As[2][256x128B],
// Bs[2][256x128B], double-buffered. Per K-tile: 4 phases, each
// {ds_read frags | 2 gload16 prefetch of t+1 -> s_barrier -> 16 MFMA w/
// setprio}; one vmcnt(0)+barrier per K-tile (loads have ~4 phases of cover).
// 128B rows: XOR-swizzle byte ^= (row&7)<<4 on pre-swizzled global source and
// identically on ds_read (same involution as attn K tile; conflict-free).
// Epilogue: bias + RoPE; q pre-scaled by 0.125*log2e; k as [B,H,T,D];
// v transposed as [B,H,D,T].
__global__ __launch_bounds__(512, 1) void gemm_qkv256(
    const unsigned short* __restrict__ A, const unsigned short* __restrict__ Bm,
    const float* __restrict__ b0, const float* __restrict__ b1, const float* __restrict__ b2,
    unsigned short* __restrict__ qb, unsigned short* __restrict__ kb,
    unsigned short* __restrict__ vtb, const float2* __restrict__ cstab)
{
    constexpr int NT = 16;                 // K/64 K-tiles
    constexpr int NXT = 12, CPX = 24;      // 16x12 = 192 blocks, 192/8 per XCD
    __shared__ __align__(16) char As[2][256 * 128];
    __shared__ __align__(16) char Bs[2][256 * 128];
    const int tid = threadIdx.x, lane = tid & 63, wid = tid >> 6;
    const int wr = wid >> 2, wc = wid & 3;   // 2M x 4N wave grid
    const int bid = blockIdx.x;
    const int swz = (bid & 7) * CPX + (bid >> 3);   // XCD-bijective (192%8==0)
    const int mt = swz / NXT;
    const int m0 = mt * 256, n0 = (swz - mt * NXT) * 256;

    f32x4 acc[8][4] = {};

    const char* Ag = (const char*)A + (size_t)m0 * 2048;
    const char* Bg = (const char*)Bm + (size_t)n0 * 2048;
    const int r0 = tid >> 3, cb = (tid & 7) * 16;

    auto stageA = [&](int k0, int bufi, int s) {
        const int r = r0 + 64 * s;
        gload16(Ag + (size_t)r * 2048 + k0 * 2 + (cb ^ ((r & 7) << 4)),
                As[bufi] + s * 8192 + wid * 1024);
    };
    auto stageB = [&](int k0, int bufi, int s) {
        const int r = r0 + 64 * s;
        gload16(Bg + (size_t)r * 2048 + k0 * 2 + (cb ^ ((r & 7) << 4)),
                Bs[bufi] + s * 8192 + wid * 1024);
    };

    // prologue: stage tile 0 fully
#pragma unroll
    for (int s = 0; s < 4; ++s) { stageA(0, 0, s); stageB(0, 0, s); }
    asm volatile("s_waitcnt vmcnt(0)" ::: "memory");
    __builtin_amdgcn_s_barrier();

    for (int t = 0; t < NT; ++t) {
        const int cur = t & 1;
        const char* Ac = As[cur];
        const char* Bc = Bs[cur];
        const int k1 = (t + 1) * 64;
        bf16x8 bfr[4][2];
#pragma unroll
        for (int p = 0; p < 4; ++p) {
            if (p == 0) {
#pragma unroll
                for (int fc = 0; fc < 4; ++fc)
#pragma unroll
                    for (int kf = 0; kf < 2; ++kf) {
                        const int r = wc * 64 + fc * 16 + (lane & 15);
                        bfr[fc][kf] = *(const bf16x8*)(Bc + r * 128 + ((kf * 64 + (lane >> 4) * 16) ^ ((r & 7) << 4)));
                    }
            }
            bf16x8 af[2][2];
#pragma unroll
            for (int fa = 0; fa < 2; ++fa)
#pragma unroll
                for (int kf = 0; kf < 2; ++kf) {
                    const int r = wr * 128 + (p * 2 + fa) * 16 + (lane & 15);
                    af[fa][kf] = *(const bf16x8*)(Ac + r * 128 + ((kf * 64 + (lane >> 4) * 16) ^ ((r & 7) << 4)));
                }
            if (t + 1 < NT) { stageA(k1, cur ^ 1, p); stageB(k1, cur ^ 1, p); }
            __builtin_amdgcn_s_barrier();
            __builtin_amdgcn_s_setprio(1);
#pragma unroll
            for (int kf = 0; kf < 2; ++kf)
#pragma unroll
                for (int fa = 0; fa < 2; ++fa)
#pragma unroll
                    for (int fc = 0; fc < 4; ++fc)
                        acc[p * 2 + fa][fc] = __builtin_amdgcn_mfma_f32_16x16x32_bf16(
                            af[fa][kf], bfr[fc][kf], acc[p * 2 + fa][fc], 0, 0, 0);
            __builtin_amdgcn_s_setprio(0);
        }
        asm volatile("s_waitcnt vmcnt(0)" ::: "memory");
        __builtin_amdgcn_s_barrier();
    }

    // epilogue: bias + RoPE, scatter q/k/v^T
    const float QSCL = 0.18033688011112042f;  // 0.125 * log2(e)
#pragma unroll
    for (int fc = 0; fc < 4; ++fc) {
        const int ng = n0 + wc * 64 + fc * 16 + (lane & 15);
        const int which = ng >> 10, nl = ng & 1023;
        const int h = nl >> 6, d = nl & 63;
        const float* bptr = (which == 0) ? b0 : (which == 1) ? b1 : b2;
        const float bias = bptr[nl];
        if (which < 2) {
            unsigned short* dst = (which == 0) ? qb : kb;
            const float qs = (which == 0) ? QSCL : 1.0f;
            const int j = d >> 1;
#pragma unroll
            for (int fr = 0; fr < 8; ++fr) {
#pragma unroll
                for (int i = 0; i < 4; ++i) {
                    const int row = m0 + wr * 128 + fr * 16 + (lane >> 4) * 4 + i;
                    const int bb = row >> 11, tt = row & 2047;
                    float v = acc[fr][fc][i] + bias;
                    float pp = __shfl_xor(v, 1);
                    const float2 cs = cstab[tt * 32 + j];
                    v = (d & 1) ? fmaf(v, cs.x, pp * cs.y) : fmaf(v, cs.x, -pp * cs.y);
                    dst[((size_t)((bb * 16 + h) * 2048 + tt)) * 64 + d] = f2bf(v * qs);
                }
            }
        } else {
#pragma unroll
            for (int fr = 0; fr < 8; ++fr) {
                const int rowb = m0 + wr * 128 + fr * 16 + (lane >> 4) * 4;
                const int bb = rowb >> 11, tt = rowb & 2047;
                ushort4 pk;
                pk.x = f2bf(acc[fr][fc][0] + bias);
                pk.y = f2bf(acc[fr][fc][1] + bias);
                pk.z = f2bf(acc[fr][fc][2] + bias);
                pk.w = f2bf(acc[fr][fc][3] + bias);
                *(ushort4*)(vtb + ((size_t)((bb * 16 + h) * 64 + d)) * 2048 + tt) = pk;
            }
        }
    }
}

// ---------------- proj GEMM: 128^2-class 2-phase dbuf + swz16 (r7) --------
// MODE 1 (BM=64): A=y[4096][1024], B=Wp[1024][1024]; bias, f32 out.
template <int MODE, int BM>
__global__ __launch_bounds__(256) void gemm_bt(
    const unsigned short* __restrict__ A, const unsigned short* __restrict__ Bm,
    const float* __restrict__ b0,
    float* __restrict__ outf)
{
    constexpr int K = 1024;
    constexpr int NIT = K / 32;
    constexpr int NR = (BM == 128) ? 4 : 2;
    __shared__ __align__(16) char As[2][BM * 64];
    __shared__ __align__(16) char Bs[2][128 * 64];
    const int tid = threadIdx.x, lane = tid & 63, wid = tid >> 6;
    const int m0 = blockIdx.y * BM, n0 = blockIdx.x * 128;
    const int wr = (BM == 128) ? ((wid >> 1) * 64) : 0;
    const int wc = (BM == 128) ? ((wid & 1) * 64) : (wid * 32);

    f32x4 acc[4][NR] = {};

    const char* Ag = (const char*)(A + (size_t)m0 * K);
    const char* Bg = (const char*)(Bm + (size_t)n0 * K);
    const int r0 = tid >> 2, cb = (tid & 3) * 16;
    const int ldsw = wid << 10;

    auto stage = [&](int k0, int bufi) {
        char* Ad = As[bufi];
        char* Bd = Bs[bufi];
        gload16(Ag + (size_t)r0 * 2048 + k0 * 2 + (cb ^ swz16(r0)), Ad + ldsw);
        if constexpr (BM == 128)
            gload16(Ag + (size_t)(r0 + 64) * 2048 + k0 * 2 + (cb ^ swz16(r0 + 64)), Ad + 4096 + ldsw);
        gload16(Bg + (size_t)r0 * 2048 + k0 * 2 + (cb ^ swz16(r0)), Bd + ldsw);
        gload16(Bg + (size_t)(r0 + 64) * 2048 + k0 * 2 + (cb ^ swz16(r0 + 64)), Bd + 4096 + ldsw);
    };

    stage(0, 0);
    __syncthreads();

    for (int it = 0; it < NIT; ++it) {
        const int cur = it & 1;
        if (it + 1 < NIT) stage((it + 1) * 32, cur ^ 1);
        const char* Ac = As[cur];
        const char* Bc = Bs[cur];
        const int fs = (lane >> 4) * 16;
        bf16x8 af[4], bfr[NR];
#pragma unroll
        for (int am = 0; am < 4; ++am) {
            const int r = wr + am * 16 + (lane & 15);
            af[am] = *(const bf16x8*)(Ac + r * 64 + (fs ^ swz16(r)));
        }
#pragma unroll
        for (int an = 0; an < NR; ++an) {
            const int r = wc + an * 16 + (lane & 15);
            bfr[an] = *(const bf16x8*)(Bc + r * 64 + (fs ^ swz16(r)));
        }
#pragma unroll
        for (int am = 0; am < 4; ++am)
#pragma unroll
            for (int an = 0; an < NR; ++an)
                acc[am][an] = __builtin_amdgcn_mfma_f32_16x16x32_bf16(af[am], bfr[an], acc[am][an], 0, 0, 0);
        __syncthreads();
    }

#pragma unroll
    for (int an = 0; an < NR; ++an) {
        const int col = n0 + wc + an * 16 + (lane & 15);
        const float bias = b0[col];
#pragma unroll
        for (int am = 0; am < 4; ++am)
#pragma unroll
            for (int i = 0; i < 4; ++i) {
                const int row = m0 + wr + am * 16 + (lane >> 4) * 4 + i;
                outf[(size_t)row * 1024 + col] = acc[am][an][i] + bias;
            }
    }
}

// ---------------- flash attention (round-4 kernel, best measured 58.6us) --
// grid: (32 q-tiles of 64, 32 bh); qtile reversed for bh>=16 so each CU's four
// resident blocks have complementary causal lengths. 4 waves, 16 q rows each.
// K staged [64 kv][64 d], V^T staged [64 d][64 kv], double-buffered,
// XOR-swizzled via pre-swizzled global source. LDS 40KB -> 4 blocks/CU.
__global__ __launch_bounds__(256) void attn_kernel(
    const unsigned short* __restrict__ qb, const unsigned short* __restrict__ kb,
    const unsigned short* __restrict__ vtb, unsigned short* __restrict__ yb)
{
    __shared__ __align__(16) unsigned short Ks[2][64 * 64];
    __shared__ __align__(16) unsigned short Vs[2][64 * 64];
    __shared__ __align__(16) unsigned short Ps[4][16 * 64];
    const int tid = threadIdx.x, lane = tid & 63, wid = tid >> 6;
    const int bh = blockIdx.y;
    const int b = bh >> 4, h = bh & 15;
    const int qt = (bh & 16) ? (31 - blockIdx.x) : blockIdx.x;
    const int q0 = qt * 64;
    const int qw = q0 + wid * 16;
    const unsigned short* Qg = qb + (size_t)bh * SEQ * HDIM;
    const char* Kg = (const char*)(kb + (size_t)bh * SEQ * HDIM);
    const char* Vg = (const char*)(vtb + (size_t)bh * HDIM * SEQ);

    bf16x8 qf[2];
#pragma unroll
    for (int kf = 0; kf < 2; ++kf)
        qf[kf] = *(const bf16x8*)(Qg + (size_t)(qw + (lane & 15)) * 64 + kf * 32 + (lane >> 4) * 8);

    f32x4 o[4] = {};                 // o[dn] : O^T[d][q]
    float mrun = -3e38f;
    float lrun = 0.0f;

    const int nt = qt + 1;
    const int cr0 = tid >> 3, cc0 = ((tid & 7) * 16) ^ ((cr0 & 7) << 4);
    const int cr1 = cr0 + 32, cc1 = ((tid & 7) * 16) ^ ((cr1 & 7) << 4);
    const int ldsw = wid << 10;

    auto stage = [&](int kt, int bufi) {
        const size_t kv0 = (size_t)kt * 64;
        gload16(Kg + (kv0 + cr0) * 128 + cc0, (char*)Ks[bufi] + ldsw);
        gload16(Kg + (kv0 + cr1) * 128 + cc1, (char*)Ks[bufi] + 4096 + ldsw);
        gload16(Vg + (size_t)cr0 * 4096 + kv0 * 2 + cc0, (char*)Vs[bufi] + ldsw);
        gload16(Vg + (size_t)cr1 * 4096 + kv0 * 2 + cc1, (char*)Vs[bufi] + 4096 + ldsw);
    };

    stage(0, 0);
    __syncthreads();

    for (int kt = 0; kt < nt; ++kt) {
        const int cur = kt & 1;
        if (kt + 1 < nt) stage(kt + 1, cur ^ 1);
        const int kv0 = kt * 64;
        {
            f32x4 s[4] = {};
            __builtin_amdgcn_s_setprio(1);
#pragma unroll
            for (int kf = 0; kf < 2; ++kf) {
                bf16x8 kfr[4];
#pragma unroll
                for (int an = 0; an < 4; ++an) {
                    const int r = an * 16 + (lane & 15);
                    kfr[an] = *(const bf16x8*)((const char*)Ks[cur] + r * 128 + ((kf * 64 + (lane >> 4) * 16) ^ ((r & 7) << 4)));
                }
#pragma unroll
                for (int an = 0; an < 4; ++an)
                    s[an] = __builtin_amdgcn_mfma_f32_16x16x32_bf16(kfr[an], qf[kf], s[an], 0, 0, 0);
            }
            __builtin_amdgcn_s_setprio(0);
            const bool need_mask = (kv0 + 63 > qw);
            const int qg = qw + (lane & 15);
            const int kbase = kv0 + ((lane >> 4) << 2);
            float p[4][4];
            float mx = -3e38f;
#pragma unroll
            for (int an = 0; an < 4; ++an)
#pragma unroll
                for (int i = 0; i < 4; ++i) {
                    float v = s[an][i];
                    if (need_mask && (kbase + an * 16 + i > qg)) v = -3e38f;
                    p[an][i] = v;
                    mx = fmaxf(mx, v);
                }
            mx = fmaxf(mx, __shfl_xor(mx, 16));
            mx = fmaxf(mx, __shfl_xor(mx, 32));
            if (!__all(mx <= mrun + 8.0f)) {
                const float mnew = fmaxf(mrun, mx);
                const float fsc = __builtin_amdgcn_exp2f(mrun - mnew);
                lrun *= fsc;
#pragma unroll
                for (int dn = 0; dn < 4; ++dn) o[dn] *= fsc;
                mrun = mnew;
            }
            float rs = 0.0f;
#pragma unroll
            for (int an = 0; an < 4; ++an)
#pragma unroll
                for (int i = 0; i < 4; ++i) {
                    p[an][i] = __builtin_amdgcn_exp2f(p[an][i] - mrun);
                    rs += p[an][i];
                }
            rs += __shfl_xor(rs, 16);
            rs += __shfl_xor(rs, 32);
            lrun += rs;
            const int ql = lane & 15;
            char* pbs = (char*)Ps[wid] + ql * 128;
            const int xr = (ql & 7) << 4;
            const int gb = (lane >> 4) << 3;
#pragma unroll
            for (int an = 0; an < 4; ++an) {
                bf16x4v pk;
                pk[0] = (__bf16)p[an][0]; pk[1] = (__bf16)p[an][1];
                pk[2] = (__bf16)p[an][2]; pk[3] = (__bf16)p[an][3];
                *(bf16x4v*)(pbs + ((an * 32 + gb) ^ xr)) = pk;
            }
            __builtin_amdgcn_s_setprio(1);
#pragma unroll
            for (int kf = 0; kf < 2; ++kf) {
                bf16x8 vf[4], pf;
#pragma unroll
                for (int dn = 0; dn < 4; ++dn) {
                    const int r = dn * 16 + (lane & 15);
                    vf[dn] = *(const bf16x8*)((const char*)Vs[cur] + r * 128 + ((kf * 64 + (lane >> 4) * 16) ^ ((r & 7) << 4)));
                }
                {
                    const int qlr = lane & 15;
                    pf = *(const bf16x8*)((const char*)Ps[wid] + qlr * 128 + ((kf * 64 + (lane >> 4) * 16) ^ ((qlr & 7) << 4)));
                }
#pragma unroll
                for (int dn = 0; dn < 4; ++dn)
                    o[dn] = __builtin_amdgcn_mfma_f32_16x16x32_bf16(vf[dn], pf, o[dn], 0, 0, 0);
            }
            __builtin_amdgcn_s_setprio(0);
        }
        __syncthreads();
    }

    {
        const float inv = 1.0f / lrun;
        const int qg = qw + (lane & 15);
        unsigned short* yrow = yb + (size_t)(b * SEQ + qg) * CDIM + h * 64;
#pragma unroll
        for (int dn = 0; dn < 4; ++dn) {
            const int d = dn * 16 + ((lane >> 4) << 2);
            bf16x4v pk;
            pk[0] = (__bf16)(o[dn][0] * inv);
            pk[1] = (__bf16)(o[dn][1] * inv);
            pk[2] = (__bf16)(o[dn][2] * inv);
            pk[3] = (__bf16)(o[dn][3] * inv);
            *(bf16x4v*)(yrow + d) = pk;
        }
    }
}

// ---------------- host ----------------

extern "C" void kernel_launch(void* const* d_in, const int* in_sizes, int n_in,
                              void* d_out, int out_size, void* d_ws, size_t ws_size,
                              hipStream_t stream) {
    (void)in_sizes; (void)n_in; (void)out_size; (void)ws_size;
    const float* x  = (const float*)d_in[0];
    const float* Wq = (const float*)d_in[1];
    const float* bq = (const float*)d_in[2];
    const float* Wk = (const float*)d_in[3];
    const float* bk = (const float*)d_in[4];
    const float* Wv = (const float*)d_in[5];
    const float* bv = (const float*)d_in[6];
    const float* Wp = (const float*)d_in[7];
    const float* bp = (const float*)d_in[8];
    float* out = (float*)d_out;

    char* ws = (char*)d_ws;
    size_t off = 0;
    auto take = [&](size_t bytes) -> char* {
        char* p = ws + off;
        off = (off + bytes + 255) & ~(size_t)255;
        return p;
    };
    float2* cstab = (float2*)take((size_t)SEQ * 32 * 8);
    unsigned short* xb   = (unsigned short*)take((size_t)4096 * 1024 * 2);
    unsigned short* wqkv = (unsigned short*)take((size_t)3 * 1024 * 1024 * 2);
    unsigned short* wpb  = (unsigned short*)take((size_t)1024 * 1024 * 2);
    unsigned short* qbuf = (unsigned short*)take((size_t)32 * SEQ * HDIM * 2);
    unsigned short* kbuf = (unsigned short*)take((size_t)32 * SEQ * HDIM * 2);
    unsigned short* vtb  = (unsigned short*)take((size_t)32 * HDIM * SEQ * 2);
    unsigned short* yb   = (unsigned short*)take((size_t)4096 * 1024 * 2);

    rope_kernel<<<256, 256, 0, stream>>>(cstab);
    cvt_kernel<<<4096, 256, 0, stream>>>(x, xb, 1048576);
    cvtw_kernel<<<4096, 256, 0, stream>>>(Wq, Wk, Wv, Wp, wqkv, wpb);

    gemm_qkv256<<<192, 512, 0, stream>>>(xb, wqkv, bq, bk, bv, qbuf, kbuf, vtb, cstab);
    dim3 g1(32, 32);
    attn_kernel<<<g1, 256, 0, stream>>>(qbuf, kbuf, vtb, yb);
    dim3 g2(8, 64);
    gemm_bt<1, 64><<<g2, 256, 0, stream>>>(yb, wpb, bp, out);
}

// Round 10
// 130.835 us; speedup vs baseline: 1.5103x; 1.0259x over previous
//
#include <hip/hip_runtime.h>

#define SEQ 2048
#define CDIM 1024
#define NHEAD 16
#define HDIM 64

typedef __bf16 bf16x8 __attribute__((ext_vector_type(8)));
typedef __bf16 bf16x4v __attribute__((ext_vector_type(4)));
typedef float f32x4 __attribute__((ext_vector_type(4)));

typedef const __attribute__((address_space(1))) char* gcp_t;
typedef __attribute__((address_space(3))) char* lcp_t;

__device__ __forceinline__ void gload16(const void* g, void* l) {
    __builtin_amdgcn_global_load_lds((gcp_t)g, (lcp_t)l, 16, 0, 0);
}

__device__ __forceinline__ unsigned short f2bf(float f) {
    unsigned int u = __float_as_uint(f);
    u += 0x7fffu + ((u >> 16) & 1u);
    return (unsigned short)(u >> 16);
}

// 64B-row LDS swizzle for the proj GEMM (proven zero conflicts r6/r7)
__device__ __forceinline__ int swz16(int r) { return ((r >> 1) & 3) << 4; }

// ---------------- precompute kernels ----------------

// one fused convert: x (1048576 float4) + 4 weight matrices (4x262144 float4)
__global__ void cvt_all(const float* __restrict__ x,
                        const float* __restrict__ Wq, const float* __restrict__ Wk,
                        const float* __restrict__ Wv, const float* __restrict__ Wp,
                        unsigned short* __restrict__ xb,
                        unsigned short* __restrict__ wqkv, unsigned short* __restrict__ wpb) {
    int i = blockIdx.x * blockDim.x + threadIdx.x;  // 2097152 total
    const float* s;
    unsigned short* d;
    int r;
    if (i < 1048576) { s = x; d = xb; r = i; }
    else {
        int j = i - 1048576;
        int which = j >> 18; r = j & 262143;
        s = (which == 0) ? Wq : (which == 1) ? Wk : (which == 2) ? Wv : Wp;
        d = (which < 3) ? (wqkv + (size_t)which * 1048576) : wpb;
    }
    float4 v = ((const float4*)s)[r];
    ushort4 o;
    o.x = f2bf(v.x); o.y = f2bf(v.y); o.z = f2bf(v.z); o.w = f2bf(v.w);
    ((ushort4*)d)[r] = o;
}

// interleaved (cos,sin) table: cstab[t*32+j] = {cos, sin}
__global__ void rope_kernel(float2* __restrict__ cstab) {
    int idx = blockIdx.x * blockDim.x + threadIdx.x;  // 2048*32
    int j = idx & 31, t = idx >> 5;
    float e = -2.0f * ((float)j - 1.0f) / 64.0f;
    float denom = (float)pow(10000.0, (double)e);
    float theta = 1.0f / denom;
    float ang = (float)t * theta;
    cstab[idx] = make_float2(cosf(ang), sinf(ang));
}

// ---------------- QKV GEMM: 256M x 192N tile, BK=64, 8 waves --------------
// C = x * Wqkv^T (M=4096, N=3072, K=1024). 16x16 = 256 blocks = 1/CU, full
// coverage, zero tail. LDS 112KB: As[2][256x128B] + Bs2[2][192x128B].
// Per K-tile: issue ALL 7 prefetch gload16 for t+1 FIRST, then 22 ds_read_b128
// + 48 MFMA/wave (compiler-interleaved, no intra-tile barriers), then one
// vmcnt(0)+s_barrier — the tile's compute (~500-700cy) covers the load latency
// so the drain is near-free. 128B rows: XOR byte ^= (row&7)<<4 on pre-swizzled
// global source and identically on ds_read (zero conflicts, r9-proven).
// Epilogue: bias + RoPE; q pre-scaled 0.125*log2e; k [B,H,T,D]; v^T [B,H,D,T].
__global__ __launch_bounds__(512, 1) void gemm_qkv(
    const unsigned short* __restrict__ A, const unsigned short* __restrict__ Bm,
    const float* __restrict__ b0, const float* __restrict__ b1, const float* __restrict__ b2,
    unsigned short* __restrict__ qb, unsigned short* __restrict__ kb,
    unsigned short* __restrict__ vtb, const float2* __restrict__ cstab)
{
    constexpr int NT = 16;                 // K/64 K-tiles
    __shared__ __align__(16) char As[2][256 * 128];
    __shared__ __align__(16) char Bs2[2][192 * 128];
    const int tid = threadIdx.x, lane = tid & 63, wid = tid >> 6;
    const int wr = wid >> 2, wc = wid & 3;   // 2M x 4N wave grid; 128x48 per wave
    const int bid = blockIdx.x;
    const int swz = (bid & 7) * 32 + (bid >> 3);   // XCD-bijective (256%8==0)
    const int mt = swz >> 4, ntl = swz & 15;
    const int m0 = mt * 256, n0 = ntl * 192;

    f32x4 acc[8][3] = {};

    const char* Ag = (const char*)A + (size_t)m0 * 2048;
    const char* Bg = (const char*)Bm + (size_t)n0 * 2048;
    const int r0 = tid >> 3, cb = (tid & 7) * 16;

    auto stage = [&](int k0, int bufi) {
#pragma unroll
        for (int v = 0; v < 4; ++v) {
            const int r = r0 + 64 * v;
            gload16(Ag + (size_t)r * 2048 + k0 * 2 + (cb ^ ((r & 7) << 4)),
                    As[bufi] + v * 8192 + wid * 1024);
        }
#pragma unroll
        for (int v = 0; v < 3; ++v) {
            const int r = r0 + 64 * v;
            gload16(Bg + (size_t)r * 2048 + k0 * 2 + (cb ^ ((r & 7) << 4)),
                    Bs2[bufi] + v * 8192 + wid * 1024);
        }
    };

    stage(0, 0);
    asm volatile("s_waitcnt vmcnt(0)" ::: "memory");
    __builtin_amdgcn_s_barrier();

    for (int t = 0; t < NT; ++t) {
        const int cur = t & 1;
        if (t + 1 < NT) stage((t + 1) * 64, cur ^ 1);   // front-loaded prefetch
        const char* Ac = As[cur];
        const char* Bc = Bs2[cur];
#pragma unroll
        for (int kf = 0; kf < 2; ++kf) {
            bf16x8 bfr[3];
#pragma unroll
            for (int fc = 0; fc < 3; ++fc) {
                const int r = wc * 48 + fc * 16 + (lane & 15);
                bfr[fc] = *(const bf16x8*)(Bc + r * 128 + ((kf * 64 + (lane >> 4) * 16) ^ ((r & 7) << 4)));
            }
            __builtin_amdgcn_s_setprio(1);
#pragma unroll
            for (int fr = 0; fr < 8; ++fr) {
                const int r = wr * 128 + fr * 16 + (lane & 15);
                bf16x8 af = *(const bf16x8*)(Ac + r * 128 + ((kf * 64 + (lane >> 4) * 16) ^ ((r & 7) << 4)));
#pragma unroll
                for (int fc = 0; fc < 3; ++fc)
                    acc[fr][fc] = __builtin_amdgcn_mfma_f32_16x16x32_bf16(af, bfr[fc], acc[fr][fc], 0, 0, 0);
            }
            __builtin_amdgcn_s_setprio(0);
        }
        asm volatile("s_waitcnt vmcnt(0)" ::: "memory");
        __builtin_amdgcn_s_barrier();
    }

    // epilogue: bias + RoPE, scatter q/k/v^T
    const float QSCL = 0.18033688011112042f;  // 0.125 * log2(e)
#pragma unroll
    for (int fc = 0; fc < 3; ++fc) {
        const int ng = n0 + wc * 48 + fc * 16 + (lane & 15);
        const int which = ng >> 10, nl = ng & 1023;
        const int h = nl >> 6, d = nl & 63;
        const float* bptr = (which == 0) ? b0 : (which == 1) ? b1 : b2;
        const float bias = bptr[nl];
        if (which < 2) {
            unsigned short* dst = (which == 0) ? qb : kb;
            const float qs = (which == 0) ? QSCL : 1.0f;
            const int j = d >> 1;
#pragma unroll
            for (int fr = 0; fr < 8; ++fr) {
#pragma unroll
                for (int i = 0; i < 4; ++i) {
                    const int row = m0 + wr * 128 + fr * 16 + (lane >> 4) * 4 + i;
                    const int bb = row >> 11, tt = row & 2047;
                    float v = acc[fr][fc][i] + bias;
                    float pp = __shfl_xor(v, 1);
                    const float2 cs = cstab[tt * 32 + j];
                    v = (d & 1) ? fmaf(v, cs.x, pp * cs.y) : fmaf(v, cs.x, -pp * cs.y);
                    dst[((size_t)((bb * 16 + h) * 2048 + tt)) * 64 + d] = f2bf(v * qs);
                }
            }
        } else {
#pragma unroll
            for (int fr = 0; fr < 8; ++fr) {
                const int rowb = m0 + wr * 128 + fr * 16 + (lane >> 4) * 4;
                const int bb = rowb >> 11, tt = rowb & 2047;
                ushort4 pk;
                pk.x = f2bf(acc[fr][fc][0] + bias);
                pk.y = f2bf(acc[fr][fc][1] + bias);
                pk.z = f2bf(acc[fr][fc][2] + bias);
                pk.w = f2bf(acc[fr][fc][3] + bias);
                *(ushort4*)(vtb + ((size_t)((bb * 16 + h) * 64 + d)) * 2048 + tt) = pk;
            }
        }
    }
}

// ---------------- proj GEMM: 64x128 2-phase dbuf + swz16 (r7) -------------
template <int MODE, int BM>
__global__ __launch_bounds__(256) void gemm_bt(
    const unsigned short* __restrict__ A, const unsigned short* __restrict__ Bm,
    const float* __restrict__ b0,
    float* __restrict__ outf)
{
    constexpr int K = 1024;
    constexpr int NIT = K / 32;
    constexpr int NR = (BM == 128) ? 4 : 2;
    __shared__ __align__(16) char As[2][BM * 64];
    __shared__ __align__(16) char Bs[2][128 * 64];
    const int tid = threadIdx.x, lane = tid & 63, wid = tid >> 6;
    const int m0 = blockIdx.y * BM, n0 = blockIdx.x * 128;
    const int wr = (BM == 128) ? ((wid >> 1) * 64) : 0;
    const int wc = (BM == 128) ? ((wid & 1) * 64) : (wid * 32);

    f32x4 acc[4][NR] = {};

    const char* Ag = (const char*)(A + (size_t)m0 * K);
    const char* Bg = (const char*)(Bm + (size_t)n0 * K);
    const int r0 = tid >> 2, cb = (tid & 3) * 16;
    const int ldsw = wid << 10;

    auto stage = [&](int k0, int bufi) {
        char* Ad = As[bufi];
        char* Bd = Bs[bufi];
        gload16(Ag + (size_t)r0 * 2048 + k0 * 2 + (cb ^ swz16(r0)), Ad + ldsw);
        if constexpr (BM == 128)
            gload16(Ag + (size_t)(r0 + 64) * 2048 + k0 * 2 + (cb ^ swz16(r0 + 64)), Ad + 4096 + ldsw);
        gload16(Bg + (size_t)r0 * 2048 + k0 * 2 + (cb ^ swz16(r0)), Bd + ldsw);
        gload16(Bg + (size_t)(r0 + 64) * 2048 + k0 * 2 + (cb ^ swz16(r0 + 64)), Bd + 4096 + ldsw);
    };

    stage(0, 0);
    __syncthreads();

    for (int it = 0; it < NIT; ++it) {
        const int cur = it & 1;
        if (it + 1 < NIT) stage((it + 1) * 32, cur ^ 1);
        const char* Ac = As[cur];
        const char* Bc = Bs[cur];
        const int fs = (lane >> 4) * 16;
        bf16x8 af[4], bfr[NR];
#pragma unroll
        for (int am = 0; am < 4; ++am) {
            const int r = wr + am * 16 + (lane & 15);
            af[am] = *(const bf16x8*)(Ac + r * 64 + (fs ^ swz16(r)));
        }
#pragma unroll
        for (int an = 0; an < NR; ++an) {
            const int r = wc + an * 16 + (lane & 15);
            bfr[an] = *(const bf16x8*)(Bc + r * 64 + (fs ^ swz16(r)));
        }
#pragma unroll
        for (int am = 0; am < 4; ++am)
#pragma unroll
            for (int an = 0; an < NR; ++an)
                acc[am][an] = __builtin_amdgcn_mfma_f32_16x16x32_bf16(af[am], bfr[an], acc[am][an], 0, 0, 0);
        __syncthreads();
    }

#pragma unroll
    for (int an = 0; an < NR; ++an) {
        const int col = n0 + wc + an * 16 + (lane & 15);
        const float bias = b0[col];
#pragma unroll
        for (int am = 0; am < 4; ++am)
#pragma unroll
            for (int i = 0; i < 4; ++i) {
                const int row = m0 + wr + am * 16 + (lane >> 4) * 4 + i;
                outf[(size_t)row * 1024 + col] = acc[am][an][i] + bias;
            }
    }
}

// ---------------- flash attention (round-4 kernel, best measured) ---------
__global__ __launch_bounds__(256) void attn_kernel(
    const unsigned short* __restrict__ qb, const unsigned short* __restrict__ kb,
    const unsigned short* __restrict__ vtb, unsigned short* __restrict__ yb)
{
    __shared__ __align__(16) unsigned short Ks[2][64 * 64];
    __shared__ __align__(16) unsigned short Vs[2][64 * 64];
    __shared__ __align__(16) unsigned short Ps[4][16 * 64];
    const int tid = threadIdx.x, lane = tid & 63, wid = tid >> 6;
    const int bh = blockIdx.y;
    const int b = bh >> 4, h = bh & 15;
    const int qt = (bh & 16) ? (31 - blockIdx.x) : blockIdx.x;
    const int q0 = qt * 64;
    const int qw = q0 + wid * 16;
    const unsigned short* Qg = qb + (size_t)bh * SEQ * HDIM;
    const char* Kg = (const char*)(kb + (size_t)bh * SEQ * HDIM);
    const char* Vg = (const char*)(vtb + (size_t)bh * HDIM * SEQ);

    bf16x8 qf[2];
#pragma unroll
    for (int kf = 0; kf < 2; ++kf)
        qf[kf] = *(const bf16x8*)(Qg + (size_t)(qw + (lane & 15)) * 64 + kf * 32 + (lane >> 4) * 8);

    f32x4 o[4] = {};                 // o[dn] : O^T[d][q]
    float mrun = -3e38f;
    float lrun = 0.0f;

    const int nt = qt + 1;
    const int cr0 = tid >> 3, cc0 = ((tid & 7) * 16) ^ ((cr0 & 7) << 4);
    const int cr1 = cr0 + 32, cc1 = ((tid & 7) * 16) ^ ((cr1 & 7) << 4);
    const int ldsw = wid << 10;

    auto stage = [&](int kt, int bufi) {
        const size_t kv0 = (size_t)kt * 64;
        gload16(Kg + (kv0 + cr0) * 128 + cc0, (char*)Ks[bufi] + ldsw);
        gload16(Kg + (kv0 + cr1) * 128 + cc1, (char*)Ks[bufi] + 4096 + ldsw);
        gload16(Vg + (size_t)cr0 * 4096 + kv0 * 2 + cc0, (char*)Vs[bufi] + ldsw);
        gload16(Vg + (size_t)cr1 * 4096 + kv0 * 2 + cc1, (char*)Vs[bufi] + 4096 + ldsw);
    };

    stage(0, 0);
    __syncthreads();

    for (int kt = 0; kt < nt; ++kt) {
        const int cur = kt & 1;
        if (kt + 1 < nt) stage(kt + 1, cur ^ 1);
        const int kv0 = kt * 64;
        {
            f32x4 s[4] = {};
            __builtin_amdgcn_s_setprio(1);
#pragma unroll
            for (int kf = 0; kf < 2; ++kf) {
                bf16x8 kfr[4];
#pragma unroll
                for (int an = 0; an < 4; ++an) {
                    const int r = an * 16 + (lane & 15);
                    kfr[an] = *(const bf16x8*)((const char*)Ks[cur] + r * 128 + ((kf * 64 + (lane >> 4) * 16) ^ ((r & 7) << 4)));
                }
#pragma unroll
                for (int an = 0; an < 4; ++an)
                    s[an] = __builtin_amdgcn_mfma_f32_16x16x32_bf16(kfr[an], qf[kf], s[an], 0, 0, 0);
            }
            __builtin_amdgcn_s_setprio(0);
            const bool need_mask = (kv0 + 63 > qw);
            const int qg = qw + (lane & 15);
            const int kbase = kv0 + ((lane >> 4) << 2);
            float p[4][4];
            float mx = -3e38f;
#pragma unroll
            for (int an = 0; an < 4; ++an)
#pragma unroll
                for (int i = 0; i < 4; ++i) {
                    float v = s[an][i];
                    if (need_mask && (kbase + an * 16 + i > qg)) v = -3e38f;
                    p[an][i] = v;
                    mx = fmaxf(mx, v);
                }
            mx = fmaxf(mx, __shfl_xor(mx, 16));
            mx = fmaxf(mx, __shfl_xor(mx, 32));
            if (!__all(mx <= mrun + 8.0f)) {
                const float mnew = fmaxf(mrun, mx);
                const float fsc = __builtin_amdgcn_exp2f(mrun - mnew);
                lrun *= fsc;
#pragma unroll
                for (int dn = 0; dn < 4; ++dn) o[dn] *= fsc;
                mrun = mnew;
            }
            float rs = 0.0f;
#pragma unroll
            for (int an = 0; an < 4; ++an)
#pragma unroll
                for (int i = 0; i < 4; ++i) {
                    p[an][i] = __builtin_amdgcn_exp2f(p[an][i] - mrun);
                    rs += p[an][i];
                }
            rs += __shfl_xor(rs, 16);
            rs += __shfl_xor(rs, 32);
            lrun += rs;
            const int ql = lane & 15;
            char* pbs = (char*)Ps[wid] + ql * 128;
            const int xr = (ql & 7) << 4;
            const int gb = (lane >> 4) << 3;
#pragma unroll
            for (int an = 0; an < 4; ++an) {
                bf16x4v pk;
                pk[0] = (__bf16)p[an][0]; pk[1] = (__bf16)p[an][1];
                pk[2] = (__bf16)p[an][2]; pk[3] = (__bf16)p[an][3];
                *(bf16x4v*)(pbs + ((an * 32 + gb) ^ xr)) = pk;
            }
            __builtin_amdgcn_s_setprio(1);
#pragma unroll
            for (int kf = 0; kf < 2; ++kf) {
                bf16x8 vf[4], pf;
#pragma unroll
                for (int dn = 0; dn < 4; ++dn) {
                    const int r = dn * 16 + (lane & 15);
                    vf[dn] = *(const bf16x8*)((const char*)Vs[cur] + r * 128 + ((kf * 64 + (lane >> 4) * 16) ^ ((r & 7) << 4)));
                }
                {
                    const int qlr = lane & 15;
                    pf = *(const bf16x8*)((const char*)Ps[wid] + qlr * 128 + ((kf * 64 + (lane >> 4) * 16) ^ ((qlr & 7) << 4)));
                }
#pragma unroll
                for (int dn = 0; dn < 4; ++dn)
                    o[dn] = __builtin_amdgcn_mfma_f32_16x16x32_bf16(vf[dn], pf, o[dn], 0, 0, 0);
            }
            __builtin_amdgcn_s_setprio(0);
        }
        __syncthreads();
    }

    {
        const float inv = 1.0f / lrun;
        const int qg = qw + (lane & 15);
        unsigned short* yrow = yb + (size_t)(b * SEQ + qg) * CDIM + h * 64;
#pragma unroll
        for (int dn = 0; dn < 4; ++dn) {
            const int d = dn * 16 + ((lane >> 4) << 2);
            bf16x4v pk;
            pk[0] = (__bf16)(o[dn][0] * inv);
            pk[1] = (__bf16)(o[dn][1] * inv);
            pk[2] = (__bf16)(o[dn][2] * inv);
            pk[3] = (__bf16)(o[dn][3] * inv);
            *(bf16x4v*)(yrow + d) = pk;
        }
    }
}

// ---------------- host ----------------

extern "C" void kernel_launch(void* const* d_in, const int* in_sizes, int n_in,
                              void* d_out, int out_size, void* d_ws, size_t ws_size,
                              hipStream_t stream) {
    (void)in_sizes; (void)n_in; (void)out_size; (void)ws_size;
    const float* x  = (const float*)d_in[0];
    const float* Wq = (const float*)d_in[1];
    const float* bq = (const float*)d_in[2];
    const float* Wk = (const float*)d_in[3];
    const float* bk = (const float*)d_in[4];
    const float* Wv = (const float*)d_in[5];
    const float* bv = (const float*)d_in[6];
    const float* Wp = (const float*)d_in[7];
    const float* bp = (const float*)d_in[8];
    float* out = (float*)d_out;

    char* ws = (char*)d_ws;
    size_t off = 0;
    auto take = [&](size_t bytes) -> char* {
        char* p = ws + off;
        off = (off + bytes + 255) & ~(size_t)255;
        return p;
    };
    float2* cstab = (float2*)take((size_t)SEQ * 32 * 8);
    unsigned short* xb   = (unsigned short*)take((size_t)4096 * 1024 * 2);
    unsigned short* wqkv = (unsigned short*)take((size_t)3 * 1024 * 1024 * 2);
    unsigned short* wpb  = (unsigned short*)take((size_t)1024 * 1024 * 2);
    unsigned short* qbuf = (unsigned short*)take((size_t)32 * SEQ * HDIM * 2);
    unsigned short* kbuf = (unsigned short*)take((size_t)32 * SEQ * HDIM * 2);
    unsigned short* vtb  = (unsigned short*)take((size_t)32 * HDIM * SEQ * 2);
    unsigned short* yb   = (unsigned short*)take((size_t)4096 * 1024 * 2);

    rope_kernel<<<256, 256, 0, stream>>>(cstab);
    cvt_all<<<8192, 256, 0, stream>>>(x, Wq, Wk, Wv, Wp, xb, wqkv, wpb);

    gemm_qkv<<<256, 512, 0, stream>>>(xb, wqkv, bq, bk, bv, qbuf, kbuf, vtb, cstab);
    dim3 g1(32, 32);
    attn_kernel<<<g1, 256, 0, stream>>>(qbuf, kbuf, vtb, yb);
    dim3 g2(8, 64);
    gemm_bt<1, 64><<<g2, 256, 0, stream>>>(yb, wpb, bp, out);
}